// Round 10
// baseline (416.232 us; speedup 1.0000x reference)
//
#include <hip/hip_runtime.h>
#include <hip/hip_bf16.h>

// Problem constants
#define BB 64     // batch
#define NT 128    // text tokens
#define NV 256    // visual tokens
#define DD 512    // feature dim (bytes per row in fp8)
#define BKB 128   // K-chunk in bytes: one 16x16x128 f8f6f4 k-step
#define EPSF 1e-7f

typedef __attribute__((ext_vector_type(8))) int i32x8;
typedef __attribute__((ext_vector_type(4))) int i32x4;
typedef __attribute__((ext_vector_type(4))) float f32x4;

__device__ __forceinline__ void glds16(const uchar* g, uchar* l) {
    __builtin_amdgcn_global_load_lds(
        (const __attribute__((address_space(1))) unsigned int*)g,
        (__attribute__((address_space(3))) unsigned int*)l, 16, 0, 0);
}

// ---------------------------------------------------------------------------
// Kernel 1: L2-normalize rows, write fp8 e4m3 (OCP). Wave per row.
// ---------------------------------------------------------------------------
__global__ __launch_bounds__(256) void k_normalize(
    const float* __restrict__ tf, const float* __restrict__ vf,
    uchar* __restrict__ tn, uchar* __restrict__ vn,
    float* __restrict__ reg_sum) {
    if (blockIdx.x == 0 && threadIdx.x == 0) *reg_sum = 0.0f;
    const int w = threadIdx.x >> 6, l = threadIdx.x & 63;
    const int row = blockIdx.x * 4 + w;
    const float* src;
    uchar* dst;
    if (row < BB * NT) {
        src = tf + (size_t)row * DD;
        dst = tn + (size_t)row * DD;
    } else {
        int r = row - BB * NT;
        src = vf + (size_t)r * DD;
        dst = vn + (size_t)r * DD;
    }
    float4 x0 = ((const float4*)src)[l * 2];
    float4 x1 = ((const float4*)src)[l * 2 + 1];
    float ss = x0.x * x0.x + x0.y * x0.y + x0.z * x0.z + x0.w * x0.w
             + x1.x * x1.x + x1.y * x1.y + x1.z * x1.z + x1.w * x1.w;
    #pragma unroll
    for (int off = 32; off; off >>= 1) ss += __shfl_xor(ss, off, 64);
    float scale = 1.0f / fmaxf(sqrtf(ss), 1e-12f);
    int p0 = __builtin_amdgcn_cvt_pk_fp8_f32(x0.x * scale, x0.y * scale, 0, 0);
    p0 = __builtin_amdgcn_cvt_pk_fp8_f32(x0.z * scale, x0.w * scale, p0, 1);
    int p1 = __builtin_amdgcn_cvt_pk_fp8_f32(x1.x * scale, x1.y * scale, 0, 0);
    p1 = __builtin_amdgcn_cvt_pk_fp8_f32(x1.z * scale, x1.w * scale, p1, 1);
    ((uint2*)dst)[l] = make_uint2((unsigned)p0, (unsigned)p1);
}

// ---------------------------------------------------------------------------
// Kernel 2: ROUND-10 -- same (i,j) pair tile 128x256, same per-wave code as
// R8 (acc[4][4], 192 unified regs/wave: the only spill-free shape), but the
// block is 4 WAVES (256 thr, 2x2 over a 128x128 sub-tile) and the two
// 128-col V panels are processed SEQUENTIALLY (8 K-steps, acc reset + row-
// max flush between panels). Why: per-SIMD reg file = 512; 192/wave -> max
// 2 waves/SIMD; an 8-wave block therefore can NEVER co-reside with another
// (explains R5/R6/R9). A 4-wave block at 66 KB LDS gives TWO INDEPENDENT
// blocks/CU: same 8 waves/CU but two barrier domains -- block B computes
// while block A drains (m114). R8's counted-vmcnt staging pattern kept
// (8 loads/stage -> vmcnt(8), never 0 mid-loop).
// ---------------------------------------------------------------------------
__global__ __launch_bounds__(256, 2) void k_gemm(
    const uchar* __restrict__ tn, const uchar* __restrict__ vn,
    const int* __restrict__ mask,
    float* __restrict__ clip_sims, float* __restrict__ reg_sum) {
    __shared__ uchar sT0[128 * BKB];   // 16 KB
    __shared__ uchar sT1[128 * BKB];   // 16 KB
    __shared__ uchar sV0[128 * BKB];   // 16 KB
    __shared__ uchar sV1[128 * BKB];   // 16 KB
    __shared__ float maxbuf[NT][4];    // [row][wc*2+jh] row-max partials
    __shared__ float redw[4];
    __shared__ float c0[2], c1[2];

    const int i = blockIdx.x, j = blockIdx.y;
    const int tid = threadIdx.x;
    const int l = tid & 63, w = tid >> 6;        // 4 waves
    const int wr = w >> 1, wc = w & 1;           // 2x2 wave grid, 64x64 each
    const int m15 = l & 15, q = l >> 4;

    const uchar* tbase = tn + (size_t)i * NT * DD;
    const uchar* vb0 = vn + (size_t)j * NV * DD;          // V rows 0..127
    const uchar* vb1 = vb0 + (size_t)128 * DD;            // V rows 128..255

    // Staging (both tiles are 128 rows x 128 B): 16B unit f -> row r = f>>3,
    // phys granule p = f&7 holds logical granule g = (p-r)&7.
    int soff[4];
    #pragma unroll
    for (int s = 0; s < 4; ++s) {
        int f = s * 256 + tid;
        int r = f >> 3, p = f & 7, g = (p - r) & 7;
        soff[s] = r * DD + g * 16;
    }

    // Fragment read addresses (rotation-mirrored, verified formulas):
    int a_b0[4], a_b1[4], b_b0[4], b_b1[4];
    #pragma unroll
    for (int rt = 0; rt < 4; ++rt) {
        int row = wr * 64 + rt * 16 + m15;
        a_b0[rt] = row * BKB + (((2 * q + row) & 7) * 16);
        a_b1[rt] = row * BKB + (((2 * q + 1 + row) & 7) * 16);
    }
    #pragma unroll
    for (int ct = 0; ct < 4; ++ct) {
        int row = wc * 64 + ct * 16 + m15;
        b_b0[ct] = row * BKB + (((2 * q + row) & 7) * 16);
        b_b1[ct] = row * BKB + (((2 * q + 1 + row) & 7) * 16);
    }

    f32x4 acc[4][4];
    #pragma unroll
    for (int rt = 0; rt < 4; ++rt)
        #pragma unroll
        for (int ct = 0; ct < 4; ++ct) acc[rt][ct] = (f32x4){0.f, 0.f, 0.f, 0.f};
    float rp = 0.0f;

    // stage step s (s = jh*4 + k): 4 T-loads + 4 V-loads per thread.
    auto stage = [&](int s) {
        uchar* dT = (s & 1) ? sT1 : sT0;
        uchar* dV = (s & 1) ? sV1 : sV0;
        const uchar* vb = (s >= 4) ? vb1 : vb0;
        const int kk = (s & 3) * BKB;
        #pragma unroll
        for (int u = 0; u < 4; ++u)
            glds16(tbase + soff[u] + kk, dT + (u * 256 + tid) * 16);
        #pragma unroll
        for (int u = 0; u < 4; ++u)
            glds16(vb + soff[u] + kk, dV + (u * 256 + tid) * 16);
    };
    auto compute = [&](int s) {
        const uchar* bT = (s & 1) ? sT1 : sT0;
        const uchar* bV = (s & 1) ? sV1 : sV0;
        i32x8 bf[4];
        #pragma unroll
        for (int ct = 0; ct < 4; ++ct) {
            i32x4 lo = *(const i32x4*)(bV + b_b0[ct]);
            i32x4 hi = *(const i32x4*)(bV + b_b1[ct]);
            bf[ct] = (i32x8){lo.x, lo.y, lo.z, lo.w, hi.x, hi.y, hi.z, hi.w};
        }
        #pragma unroll
        for (int rt = 0; rt < 4; ++rt) {
            i32x4 lo = *(const i32x4*)(bT + a_b0[rt]);
            i32x4 hi = *(const i32x4*)(bT + a_b1[rt]);
            i32x8 a = (i32x8){lo.x, lo.y, lo.z, lo.w, hi.x, hi.y, hi.z, hi.w};
            #pragma unroll
            for (int ct = 0; ct < 4; ++ct)
                acc[rt][ct] = __builtin_amdgcn_mfma_scale_f32_16x16x128_f8f6f4(
                    a, bf[ct], acc[rt][ct],
                    0 /*A fmt=fp8*/, 0 /*B fmt=fp8*/,
                    0, 127 /*scaleA=1.0*/, 0, 127 /*scaleB=1.0*/);
        }
    };
    // flush panel jh: reg-loss partial + row max (over this panel's 128
    // cols) into maxbuf[row][wc*2+jh]; reset acc for the next panel.
    auto flush = [&](int jh) {
        #pragma unroll
        for (int rt = 0; rt < 4; ++rt)
            #pragma unroll
            for (int ct = 0; ct < 4; ++ct)
                #pragma unroll
                for (int r = 0; r < 4; ++r) {
                    float m = fminf(acc[rt][ct][r], 0.0f);
                    rp = fmaf(m, m, rp);
                }
        #pragma unroll
        for (int rt = 0; rt < 4; ++rt)
            #pragma unroll
            for (int r = 0; r < 4; ++r) {
                float m = acc[rt][0][r];
                #pragma unroll
                for (int ct = 1; ct < 4; ++ct) m = fmaxf(m, acc[rt][ct][r]);
                #pragma unroll
                for (int msk = 1; msk < 16; msk <<= 1)
                    m = fmaxf(m, __shfl_xor(m, msk, 64));
                if (m15 == 0)
                    maxbuf[wr * 64 + rt * 16 + q * 4 + r][wc * 2 + jh] = m;
            }
        #pragma unroll
        for (int rt = 0; rt < 4; ++rt)
            #pragma unroll
            for (int ct = 0; ct < 4; ++ct) acc[rt][ct] = (f32x4){0.f, 0.f, 0.f, 0.f};
    };

    // --- 8-step schedule, R8's counted-vmcnt pattern (8 loads/stage) ------
    stage(0);
    stage(1);
    #pragma unroll
    for (int s = 0; s < 8; ++s) {
        if (s < 7) { asm volatile("s_waitcnt vmcnt(8)" ::: "memory"); }
        else       { asm volatile("s_waitcnt vmcnt(0)" ::: "memory"); }
        __builtin_amdgcn_s_barrier();
        asm volatile("" ::: "memory");
        compute(s);
        if (s == 3) flush(0);
        if (s == 7) flush(1);
        asm volatile("" ::: "memory");
        __builtin_amdgcn_s_barrier();
        if (s + 2 < 8) stage(s + 2);
    }

    // Final epilogue: reg-loss reduce + fused clip (complete rows: max over
    // all 4 maxbuf slots = both wc groups x both jh panels).
    #pragma unroll
    for (int off = 32; off; off >>= 1) rp += __shfl_down(rp, off, 64);
    if (l == 0) redw[w] = rp;
    __syncthreads();

    if (tid < NT) {
        float rm = fmaxf(fmaxf(maxbuf[tid][0], maxbuf[tid][1]),
                         fmaxf(maxbuf[tid][2], maxbuf[tid][3]));
        float mf = (float)mask[i * NT + tid];
        float v = rm * mf;
        #pragma unroll
        for (int off = 32; off; off >>= 1) {
            v += __shfl_down(v, off, 64);
            mf += __shfl_down(mf, off, 64);
        }
        if (l == 0) { c0[w] = v; c1[w] = mf; }
    }
    __syncthreads();
    if (tid == 0) {
        clip_sims[i * BB + j] = (c0[0] + c0[1]) / fmaxf(c1[0] + c1[1], EPSF);
        float s = redw[0] + redw[1] + redw[2] + redw[3];
        atomicAdd(reg_sum, s);
    }
}

// ---------------------------------------------------------------------------
// Kernel 3: final scalar loss. Single block, 256 threads.
// ---------------------------------------------------------------------------
__global__ __launch_bounds__(256) void k_loss(
    const float* __restrict__ clip_sims, const float* __restrict__ reg_sum,
    float* __restrict__ out) {
    __shared__ float sc[BB][BB + 1];
    __shared__ float lrow[BB], lcol[BB];
    int tid = threadIdx.x;
    for (int idx = tid; idx < BB * BB; idx += 256)
        sc[idx / BB][idx % BB] = clip_sims[idx];
    __syncthreads();
    if (tid < BB) {
        int i = tid;
        float m = sc[i][0];
        #pragma unroll
        for (int j = 1; j < BB; ++j) m = fmaxf(m, sc[i][j]);
        float s = 0.0f;
        #pragma unroll
        for (int j = 0; j < BB; ++j) s += expf(sc[i][j] - m);
        lrow[i] = m + logf(s) - sc[i][i];
    } else if (tid < 2 * BB) {
        int i = tid - BB;
        float m = sc[0][i];
        #pragma unroll
        for (int j = 1; j < BB; ++j) m = fmaxf(m, sc[j][i]);
        float s = 0.0f;
        #pragma unroll
        for (int j = 0; j < BB; ++j) s += expf(sc[j][i] - m);
        lcol[i] = m + logf(s) - sc[i][i];
    }
    __syncthreads();
    if (tid == 0) {
        float tot = 0.0f;
        for (int i = 0; i < BB; ++i) tot += lrow[i] + lcol[i];
        float contrastive = tot / (2.0f * BB);
        double denom = (double)BB * BB * NT * NV;  // 134217728
        float reg = 0.15f * (float)((double)reg_sum[0] / denom);
        out[0] = contrastive + reg;
    }
}

// ---------------------------------------------------------------------------
extern "C" void kernel_launch(void* const* d_in, const int* in_sizes, int n_in,
                              void* d_out, int out_size, void* d_ws, size_t ws_size,
                              hipStream_t stream) {
    const float* tf = (const float*)d_in[0];   // (B, NT, D) fp32
    const float* vf = (const float*)d_in[1];   // (B, NV, D) fp32
    const int* mask = (const int*)d_in[2];     // (B, NT) int32
    float* out = (float*)d_out;                // scalar fp32

    char* ws = (char*)d_ws;
    size_t tn_bytes = (size_t)BB * NT * DD;              // 4 MB fp8
    size_t vn_bytes = (size_t)BB * NV * DD;              // 8 MB fp8
    size_t cs_bytes = (size_t)BB * BB * sizeof(float);   // 16 KB

    uchar* tn = (uchar*)ws;
    uchar* vn = (uchar*)(ws + tn_bytes);
    float* clip_sims = (float*)(ws + tn_bytes + vn_bytes);
    float* reg_sum = (float*)(ws + tn_bytes + vn_bytes + cs_bytes);

    k_normalize<<<(BB * NT + BB * NV) / 4, 256, 0, stream>>>(tf, vf, tn, vn, reg_sum);
    k_gemm<<<dim3(BB, BB), 256, 0, stream>>>(tn, vn, mask, clip_sims, reg_sum);
    k_loss<<<1, 256, 0, stream>>>(clip_sims, reg_sum, out);
}